// Round 1
// baseline (126.094 us; speedup 1.0000x reference)
//
#include <hip/hip_runtime.h>
#include <math.h>

#define BB 4
#define HH 256
#define WW 256
#define NN (BB*HH*WW)          // 262144
#define BIGF 1.0e6f

// ws layout (floats):
//  [0..5]  accumulators: 0=intersection 1=sum_p 2=sum_t 3=bce 4=focal 5=boundary
//  [16            .. 16+NN)   g^2 for pred_bin
//  [16+NN         .. 16+2NN)  g^2 for targ_bin
#define G_OFF 16

// ---------------------------------------------------------------------------
// Kernel 1: vertical 1D EDT (two scans per column) for both binary images.
// 2048 threads: img (2) x batch (4) x col (256). Coalesced: consecutive c ->
// consecutive addresses at every row step. Also zeroes the accumulators.
// ---------------------------------------------------------------------------
__global__ __launch_bounds__(256)
void edt_vertical(const float* __restrict__ pred,
                  const float* __restrict__ targ,
                  float* __restrict__ ws) {
    if (blockIdx.x == 0 && threadIdx.x < 8) ws[threadIdx.x] = 0.0f;

    int t   = blockIdx.x * 256 + threadIdx.x;   // 0..2047
    int img = t >> 10;                          // 0 = pred_bin, 1 = targ_bin
    int rem = t & 1023;
    int b   = rem >> 8;
    int c   = rem & 255;

    const float* s = (img ? targ : pred) + b * (HH * WW) + c;
    float*       g = ws + G_OFF + img * NN + b * (HH * WW) + c;

    // down scan: d = zero ? 0 : carry+1
    float carry = BIGF;
    #pragma unroll 4
    for (int i = 0; i < HH; ++i) {
        float x = s[i * WW];
        bool  z = img ? (x == 0.0f) : (x <= 0.5f);   // binary==0
        float d = z ? 0.0f : (carry + 1.0f);
        g[i * WW] = d;
        carry = d;
    }
    // up scan, combine with stored down value, store squared
    carry = BIGF;
    #pragma unroll 4
    for (int i = HH - 1; i >= 0; --i) {
        float x = s[i * WW];
        bool  z = img ? (x == 0.0f) : (x <= 0.5f);
        float d = z ? 0.0f : (carry + 1.0f);
        carry = d;
        float gm = fminf(g[i * WW], d);
        g[i * WW] = gm * gm;
    }
}

// ---------------------------------------------------------------------------
// Kernel 2: per-row horizontal EDT min + all elementwise loss terms, fused.
// One block per (b,row); thread j handles output column j.
// ---------------------------------------------------------------------------
__global__ __launch_bounds__(256)
void row_fused(const float* __restrict__ pred,
               const float* __restrict__ targ,
               float* __restrict__ ws) {
    __shared__ float g2p[WW];
    __shared__ float g2t[WW];
    __shared__ float red[4][6];

    const float* gbase = ws + G_OFF;
    int row  = blockIdx.x;          // 0 .. BB*HH-1
    int j    = threadIdx.x;         // 0 .. 255
    int base = row * WW;

    g2p[j] = gbase[base + j];
    g2t[j] = gbase[NN + base + j];
    __syncthreads();

    // horizontal min: d2 = min_c g2[c] + (j-c)^2  (broadcast LDS reads: free)
    float d2p = 3.0e38f, d2t = 3.0e38f;
    #pragma unroll 8
    for (int c = 0; c < WW; ++c) {
        float dj = (float)(j - c);
        float q  = dj * dj;
        d2p = fminf(d2p, g2p[c] + q);
        d2t = fminf(d2t, g2t[c] + q);
    }
    float bdiff = fabsf(sqrtf(d2p) - sqrtf(d2t));

    // elementwise terms for pixel (row, j)
    float x = pred[base + j];
    float t = targ[base + j];
    float p = 1.0f / (1.0f + expf(-x));

    float ax  = fabsf(x);
    float l1p = log1pf(expf(-ax));
    float bce_el = fmaxf(x, 0.0f) - x * t + l1p;          // BCEWithLogits
    float lsx  = fminf(x, 0.0f) - l1p;                     // log(p)
    float lsnx = -fmaxf(x, 0.0f) - l1p;                    // log(1-p)
    float bce_f = -(t * lsx + (1.0f - t) * lsnx);
    float pt  = p * t + (1.0f - p) * (1.0f - t);
    float om  = 1.0f - pt;
    float focal_el = om * om * bce_f;                      // alpha=1, gamma=2

    float vals[6] = { p * t, p, t, bce_el, focal_el, bdiff };

    int lane = threadIdx.x & 63;
    int wave = threadIdx.x >> 6;
    #pragma unroll
    for (int k = 0; k < 6; ++k) {
        float v = vals[k];
        #pragma unroll
        for (int off = 32; off > 0; off >>= 1)
            v += __shfl_down(v, off, 64);
        if (lane == 0) red[wave][k] = v;
    }
    __syncthreads();
    if (threadIdx.x < 6) {
        float s = red[0][threadIdx.x] + red[1][threadIdx.x]
                + red[2][threadIdx.x] + red[3][threadIdx.x];
        atomicAdd(&ws[threadIdx.x], s);
    }
}

// ---------------------------------------------------------------------------
// Kernel 3: combine accumulators -> scalar loss
// ---------------------------------------------------------------------------
__global__ void finalize(const float* __restrict__ ws, float* __restrict__ out) {
    float inter = ws[0], sp = ws[1], st = ws[2];
    float bce = ws[3], foc = ws[4], bnd = ws[5];
    float invN = 1.0f / (float)NN;
    float dice = 1.0f - (2.0f * inter + 1.0f) / (sp + st + 1.0f);
    float loss = 0.5f * dice + 0.5f * (bce * invN)
               + 0.1f * (bnd * invN) + 0.2f * (foc * invN);
    out[0] = loss;
}

extern "C" void kernel_launch(void* const* d_in, const int* in_sizes, int n_in,
                              void* d_out, int out_size, void* d_ws, size_t ws_size,
                              hipStream_t stream) {
    const float* pred = (const float*)d_in[0];
    const float* targ = (const float*)d_in[1];
    float* ws = (float*)d_ws;

    edt_vertical<<<8, 256, 0, stream>>>(pred, targ, ws);
    row_fused<<<BB * HH, 256, 0, stream>>>(pred, targ, ws);
    finalize<<<1, 1, 0, stream>>>(ws, (float*)d_out);
}

// Round 2
// 77.613 us; speedup vs baseline: 1.6246x; 1.6246x over previous
//
#include <hip/hip_runtime.h>
#include <math.h>

#define BB 4
#define HH 256
#define WW 256
#define NN (BB*HH*WW)          // 262144
typedef unsigned long long u64;

// ws layout:
//   float[0..5]  accumulators: 0=intersection 1=sum_p 2=sum_t 3=bce 4=focal 5=boundary
//   byte 256 ...: column-major zero masks, u64 maskT[img][b][c][w]
//                 2*4*256*4 = 8192 u64 = 64 KB. bit r of word w = row 64w+r is "zero".
#define MASK_OFF_BYTES 256
#define SENT 100000            // no-zero-in-column sentinel (g^2 ~1e10 >> 130050 max real)

// ---------------------------------------------------------------------------
// Kernel A: build column-major zero bitmasks for both thresholded images.
// thread = (img, b, word w, col c); 64 coalesced row loads -> one u64.
// Also zeroes the 6 accumulators.
// ---------------------------------------------------------------------------
__global__ __launch_bounds__(256)
void build_masks(const float* __restrict__ pred,
                 const float* __restrict__ targ,
                 float* __restrict__ ws) {
    int t = blockIdx.x * 256 + threadIdx.x;   // 0..8191
    if (t < 8) ws[t] = 0.0f;

    int c   = t & 255;
    int w   = (t >> 8) & 3;
    int b   = (t >> 10) & 3;
    int img = t >> 12;

    // zero predicate: pred_bin = (x > 0.5) -> zero iff x <= 0.5; targ in {0,1} -> same test
    const float* s = (img ? targ : pred) + b * (HH * WW) + (w * 64) * WW + c;
    u64 m = 0;
    #pragma unroll
    for (int r = 0; r < 64; ++r) {
        float x = s[r * WW];
        m |= ((u64)(x <= 0.5f)) << r;
    }
    u64* maskT = (u64*)((char*)ws + MASK_OFF_BYTES);
    maskT[(((img * BB + b) * WW + c) << 2) + w] = m;
}

// ---------------------------------------------------------------------------
// Kernel B: per-(b, 4-row band) fused kernel.
//   phase 2: vertical EDT via register bit-scans (O(1) per row, no LDS)
//   phase 3: horizontal min-plus from LDS broadcast reads
//   phase 4: all elementwise loss terms + block reduction + atomics
// ---------------------------------------------------------------------------
__global__ __launch_bounds__(256)
void band_fused(const float* __restrict__ pred,
                const float* __restrict__ targ,
                float* __restrict__ ws) {
    __shared__ float2 G[4][WW];     // [row-in-band][col] = (g2_pred, g2_targ)
    __shared__ float red[4][6];

    int blk  = blockIdx.x;          // 0..255
    int b    = blk >> 6;
    int band = blk & 63;
    int i0   = band << 2;           // first row of band
    int wq   = i0 >> 6;             // word containing the band (uniform)
    int o0   = i0 & 63;             // bit offset (<=60, so o0+3 <= 63)
    int c    = threadIdx.x;         // this thread's column for phase 2

    const u64* maskT = (const u64*)((const char*)ws + MASK_OFF_BYTES);

    float g2v[2][4];
    #pragma unroll
    for (int img = 0; img < 2; ++img) {
        const u64* mp = maskT + (((img * BB + b) * WW + c) << 2);
        u64 M0 = mp[0], M1 = mp[1], M2 = mp[2], M3 = mp[3];

        // per-word first (lowest) set-bit global index, sentinel SENT
        int t1 = __ffsll(M1), t2 = __ffsll(M2), t3 = __ffsll(M3);
        int f1 = t1 ? 64 + t1 - 1  : SENT;
        int f2 = t2 ? 128 + t2 - 1 : SENT;
        int f3 = t3 ? 192 + t3 - 1 : SENT;
        // per-word last (highest) set-bit global index, sentinel -SENT
        int r0 = __ffsll(__brevll(M0));
        int r1 = __ffsll(__brevll(M1));
        int r2 = __ffsll(__brevll(M2));
        int l0 = r0 ? 64 - r0  : -SENT;
        int l1 = r1 ? 128 - r1 : -SENT;
        int l2 = r2 ? 192 - r2 : -SENT;

        // suffix-firsts (words above wq) / prefix-lasts (words below wq)
        int s3 = f3;
        int s2 = min(f2, s3);
        int s1 = min(f1, s2);
        int NF = (wq == 0) ? s1 : (wq == 1) ? s2 : (wq == 2) ? s3 : SENT;
        int q0 = l0;
        int q1 = max(q0, l1);
        int q2 = max(q1, l2);
        int PB = (wq == 0) ? -SENT : (wq == 1) ? q0 : (wq == 2) ? q1 : q2;
        u64 Mq = (wq == 0) ? M0 : (wq == 1) ? M1 : (wq == 2) ? M2 : M3;

        #pragma unroll
        for (int kk = 0; kk < 4; ++kk) {
            int i = i0 + kk, o = o0 + kk;            // o <= 63
            u64 sh  = Mq >> o;                       // bits at/above i within word
            int tn  = __ffsll(sh);
            int n   = tn ? i + tn - 1 : NF;          // nearest zero row >= i
            u64 shl = Mq << (63 - o);                // bits at/below i within word
            int tp  = __ffsll(__brevll(shl));
            int p   = tp ? i - (tp - 1) : PB;        // nearest zero row <= i
            int g   = min(n - i, i - p);
            g2v[img][kk] = (float)g * (float)g;
        }
    }
    #pragma unroll
    for (int kk = 0; kk < 4; ++kk)
        G[kk][c] = make_float2(g2v[0][kk], g2v[1][kk]);
    __syncthreads();

    // ---- phase 3: horizontal pass. thread = (row = tid>>6, j in {j0, j0+64, j0+128, j0+192})
    int row = threadIdx.x >> 6;     // uniform within each wave
    int j0  = threadIdx.x & 63;
    int i   = i0 + row;

    float d2p[4] = {1e30f, 1e30f, 1e30f, 1e30f};
    float d2t[4] = {1e30f, 1e30f, 1e30f, 1e30f};
    for (int cc = 0; cc < WW; ++cc) {
        float2 g = G[row][cc];      // broadcast LDS read (same addr per wave)
        float fd = (float)(j0 - cc);
        #pragma unroll
        for (int k = 0; k < 4; ++k) {
            float d = fd + (float)(64 * k);
            float q = d * d;
            d2p[k] = fminf(d2p[k], g.x + q);
            d2t[k] = fminf(d2t[k], g.y + q);
        }
    }

    // ---- phase 4: elementwise loss terms for the thread's 4 pixels
    float sPT = 0.0f, sP = 0.0f, sT = 0.0f, sBCE = 0.0f, sFOC = 0.0f, sBND = 0.0f;
    #pragma unroll
    for (int k = 0; k < 4; ++k) {
        int j   = j0 + 64 * k;
        int idx = (b * HH + i) * WW + j;
        float x = pred[idx];
        float t = targ[idx];

        sBND += fabsf(sqrtf(d2p[k]) - sqrtf(d2t[k]));

        float p   = 1.0f / (1.0f + expf(-x));
        float ax  = fabsf(x);
        float l1p = log1pf(expf(-ax));
        float bce_el = fmaxf(x, 0.0f) - x * t + l1p;      // BCEWithLogits
        float lsx  = fminf(x, 0.0f) - l1p;                 // log(p)
        float lsnx = -fmaxf(x, 0.0f) - l1p;                // log(1-p)
        float bce_f = -(t * lsx + (1.0f - t) * lsnx);
        float pt = p * t + (1.0f - p) * (1.0f - t);
        float om = 1.0f - pt;

        sPT  += p * t;
        sP   += p;
        sT   += t;
        sBCE += bce_el;
        sFOC += om * om * bce_f;                           // alpha=1, gamma=2
    }

    float vals[6] = { sPT, sP, sT, sBCE, sFOC, sBND };
    int lane = threadIdx.x & 63;
    int wave = threadIdx.x >> 6;
    #pragma unroll
    for (int k = 0; k < 6; ++k) {
        float v = vals[k];
        #pragma unroll
        for (int off = 32; off > 0; off >>= 1)
            v += __shfl_down(v, off, 64);
        if (lane == 0) red[wave][k] = v;
    }
    __syncthreads();
    if (threadIdx.x < 6) {
        float s = red[0][threadIdx.x] + red[1][threadIdx.x]
                + red[2][threadIdx.x] + red[3][threadIdx.x];
        atomicAdd(&ws[threadIdx.x], s);
    }
}

// ---------------------------------------------------------------------------
// Kernel C: combine accumulators -> scalar loss
// ---------------------------------------------------------------------------
__global__ void finalize(const float* __restrict__ ws, float* __restrict__ out) {
    float inter = ws[0], sp = ws[1], st = ws[2];
    float bce = ws[3], foc = ws[4], bnd = ws[5];
    float invN = 1.0f / (float)NN;
    float dice = 1.0f - (2.0f * inter + 1.0f) / (sp + st + 1.0f);
    float loss = 0.5f * dice + 0.5f * (bce * invN)
               + 0.1f * (bnd * invN) + 0.2f * (foc * invN);
    out[0] = loss;
}

extern "C" void kernel_launch(void* const* d_in, const int* in_sizes, int n_in,
                              void* d_out, int out_size, void* d_ws, size_t ws_size,
                              hipStream_t stream) {
    const float* pred = (const float*)d_in[0];
    const float* targ = (const float*)d_in[1];
    float* ws = (float*)d_ws;

    build_masks<<<32, 256, 0, stream>>>(pred, targ, ws);
    band_fused<<<BB * 64, 256, 0, stream>>>(pred, targ, ws);
    finalize<<<1, 1, 0, stream>>>(ws, (float*)d_out);
}

// Round 3
// 70.155 us; speedup vs baseline: 1.7974x; 1.1063x over previous
//
#include <hip/hip_runtime.h>
#include <math.h>

#define BB 4
#define HH 256
#define WW 256
#define NN (BB*HH*WW)          // 262144
typedef unsigned long long u64;

// ws layout:
//   float[0..5]  accumulators: 0=intersection 1=sum_p 2=sum_t 3=bce 4=focal 5=boundary
//   float[6]     completion counter (as unsigned)
//   byte 256 ...: column-major zero masks, u64 maskT[img][b][c][w]
//                 2*4*256*4 = 8192 u64 = 64 KB. bit r of word w = row 64w+r is "zero".
#define MASK_OFF_BYTES 256
#define SENT 100000            // no-zero-in-column sentinel (g^2 ~1e10 >> 130050 max real)

// ---------------------------------------------------------------------------
// Kernel A: build column-major zero bitmasks for both thresholded images.
// thread = (img, b, word w, col c); 64 coalesced row loads -> one u64.
// 64 blocks x 128 threads so the 2 MB cold read spreads over 64 CUs.
// Also zeroes the 6 accumulators + completion counter.
// ---------------------------------------------------------------------------
__global__ __launch_bounds__(128)
void build_masks(const float* __restrict__ pred,
                 const float* __restrict__ targ,
                 float* __restrict__ ws) {
    int t = blockIdx.x * 128 + threadIdx.x;   // 0..8191
    if (t < 9) ws[t] = 0.0f;

    int c   = t & 255;
    int w   = (t >> 8) & 3;
    int b   = (t >> 10) & 3;
    int img = t >> 12;

    // zero predicate: pred_bin = (x > 0.5) -> zero iff x <= 0.5; targ in {0,1} -> same test
    const float* s = (img ? targ : pred) + b * (HH * WW) + (w * 64) * WW + c;
    u64 m = 0;
    #pragma unroll
    for (int r = 0; r < 64; ++r) {
        float x = s[r * WW];
        m |= ((u64)(x <= 0.5f)) << r;
    }
    u64* maskT = (u64*)((char*)ws + MASK_OFF_BYTES);
    maskT[(((img * BB + b) * WW + c) << 2) + w] = m;
}

// ---------------------------------------------------------------------------
// Kernel B: per-(b, 4-row band) fused kernel.
//   phase 2: vertical EDT via register bit-scans (O(1) per row, no LDS)
//   phase 3: horizontal min-plus, outward scan with exact early exit
//   phase 4: elementwise loss terms + block reduction + atomics
//   phase 5: last-finishing block combines accumulators -> d_out
// ---------------------------------------------------------------------------
__global__ __launch_bounds__(256)
void band_fused(const float* __restrict__ pred,
                const float* __restrict__ targ,
                float* __restrict__ ws,
                float* __restrict__ out) {
    __shared__ float2 G[4][WW];     // [row-in-band][col] = (g2_pred, g2_targ)
    __shared__ float red[4][6];
    __shared__ int amLast;

    int blk  = blockIdx.x;          // 0..255
    int b    = blk >> 6;
    int band = blk & 63;
    int i0   = band << 2;           // first row of band
    int wq   = i0 >> 6;             // word containing the band (uniform)
    int o0   = i0 & 63;             // bit offset (<=60, so o0+3 <= 63)
    int c    = threadIdx.x;         // this thread's column

    const u64* maskT = (const u64*)((const char*)ws + MASK_OFF_BYTES);

    // ---- phase 2: vertical distances for this column, 4 band rows, both images
    float g2v[2][4];
    #pragma unroll
    for (int img = 0; img < 2; ++img) {
        const u64* mp = maskT + (((img * BB + b) * WW + c) << 2);
        u64 M0 = mp[0], M1 = mp[1], M2 = mp[2], M3 = mp[3];

        // per-word first (lowest) set-bit global index, sentinel SENT
        int t1 = __ffsll(M1), t2 = __ffsll(M2), t3 = __ffsll(M3);
        int f1 = t1 ? 64 + t1 - 1  : SENT;
        int f2 = t2 ? 128 + t2 - 1 : SENT;
        int f3 = t3 ? 192 + t3 - 1 : SENT;
        // per-word last (highest) set-bit global index, sentinel -SENT
        int r0 = __ffsll(__brevll(M0));
        int r1 = __ffsll(__brevll(M1));
        int r2 = __ffsll(__brevll(M2));
        int l0 = r0 ? 64 - r0  : -SENT;
        int l1 = r1 ? 128 - r1 : -SENT;
        int l2 = r2 ? 192 - r2 : -SENT;

        // suffix-firsts (words above wq) / prefix-lasts (words below wq)
        int s3 = f3;
        int s2 = min(f2, s3);
        int s1 = min(f1, s2);
        int NF = (wq == 0) ? s1 : (wq == 1) ? s2 : (wq == 2) ? s3 : SENT;
        int q0 = l0;
        int q1 = max(q0, l1);
        int q2 = max(q1, l2);
        int PB = (wq == 0) ? -SENT : (wq == 1) ? q0 : (wq == 2) ? q1 : q2;
        u64 Mq = (wq == 0) ? M0 : (wq == 1) ? M1 : (wq == 2) ? M2 : M3;

        #pragma unroll
        for (int kk = 0; kk < 4; ++kk) {
            int i = i0 + kk, o = o0 + kk;            // o <= 63
            u64 sh  = Mq >> o;                       // bits at/above i within word
            int tn  = __ffsll(sh);
            int n   = tn ? i + tn - 1 : NF;          // nearest zero row >= i
            u64 shl = Mq << (63 - o);                // bits at/below i within word
            int tp  = __ffsll(__brevll(shl));
            int p   = tp ? i - (tp - 1) : PB;        // nearest zero row <= i
            int g   = min(n - i, i - p);
            g2v[img][kk] = (float)g * (float)g;
        }
    }
    #pragma unroll
    for (int kk = 0; kk < 4; ++kk)
        G[kk][c] = make_float2(g2v[0][kk], g2v[1][kk]);
    __syncthreads();

    // ---- phase 3: horizontal min-plus, outward scan from j with exact early exit.
    // Any candidate at radius r has value >= r^2, so once r^2 >= current-best
    // (for every lane of the wave) no improvement is possible.
    int j = threadIdx.x;
    float d2p[4], d2t[4];
    #pragma unroll
    for (int k = 0; k < 4; ++k) {    // r = 0 candidate
        float2 g = G[k][j];
        d2p[k] = g.x; d2t[k] = g.y;
    }
    for (int r = 1; r < WW; ++r) {
        float r2 = (float)(r * r);
        float dmax = fmaxf(fmaxf(fmaxf(d2p[0], d2p[1]), fmaxf(d2p[2], d2p[3])),
                           fmaxf(fmaxf(d2t[0], d2t[1]), fmaxf(d2t[2], d2t[3])));
        if (__all(r2 >= dmax)) break;
        int lo = j - r, hi = j + r;
        if (lo >= 0) {
            #pragma unroll
            for (int k = 0; k < 4; ++k) {
                float2 g = G[k][lo];
                d2p[k] = fminf(d2p[k], g.x + r2);
                d2t[k] = fminf(d2t[k], g.y + r2);
            }
        }
        if (hi < WW) {
            #pragma unroll
            for (int k = 0; k < 4; ++k) {
                float2 g = G[k][hi];
                d2p[k] = fminf(d2p[k], g.x + r2);
                d2t[k] = fminf(d2t[k], g.y + r2);
            }
        }
    }

    // ---- phase 4: elementwise loss terms for this thread's 4 pixels (rows i0..i0+3, col j)
    float sPT = 0.0f, sP = 0.0f, sT = 0.0f, sBCE = 0.0f, sFOC = 0.0f, sBND = 0.0f;
    #pragma unroll
    for (int k = 0; k < 4; ++k) {
        int idx = (b * HH + (i0 + k)) * WW + j;
        float x = pred[idx];
        float t = targ[idx];

        sBND += fabsf(sqrtf(d2p[k]) - sqrtf(d2t[k]));

        float p   = 1.0f / (1.0f + expf(-x));
        float ax  = fabsf(x);
        float l1p = log1pf(expf(-ax));
        float bce_el = fmaxf(x, 0.0f) - x * t + l1p;      // BCEWithLogits
        float lsx  = fminf(x, 0.0f) - l1p;                 // log(p)
        float lsnx = -fmaxf(x, 0.0f) - l1p;                // log(1-p)
        float bce_f = -(t * lsx + (1.0f - t) * lsnx);
        float pt = p * t + (1.0f - p) * (1.0f - t);
        float om = 1.0f - pt;

        sPT  += p * t;
        sP   += p;
        sT   += t;
        sBCE += bce_el;
        sFOC += om * om * bce_f;                           // alpha=1, gamma=2
    }

    float vals[6] = { sPT, sP, sT, sBCE, sFOC, sBND };
    int lane = threadIdx.x & 63;
    int wave = threadIdx.x >> 6;
    #pragma unroll
    for (int k = 0; k < 6; ++k) {
        float v = vals[k];
        #pragma unroll
        for (int off = 32; off > 0; off >>= 1)
            v += __shfl_down(v, off, 64);
        if (lane == 0) red[wave][k] = v;
    }
    __syncthreads();
    if (threadIdx.x < 6) {
        float s = red[0][threadIdx.x] + red[1][threadIdx.x]
                + red[2][threadIdx.x] + red[3][threadIdx.x];
        atomicAdd(&ws[threadIdx.x], s);
        __threadfence();               // make this block's partials visible
    }
    __syncthreads();

    // ---- phase 5: last block to finish combines accumulators
    if (threadIdx.x == 0) {
        unsigned old = atomicAdd((unsigned*)(ws + 6), 1u);
        amLast = (old == 255u);
    }
    __syncthreads();
    if (amLast && threadIdx.x == 0) {
        float inter = atomicAdd(&ws[0], 0.0f);
        float sp    = atomicAdd(&ws[1], 0.0f);
        float st    = atomicAdd(&ws[2], 0.0f);
        float bce   = atomicAdd(&ws[3], 0.0f);
        float foc   = atomicAdd(&ws[4], 0.0f);
        float bnd   = atomicAdd(&ws[5], 0.0f);
        float invN = 1.0f / (float)NN;
        float dice = 1.0f - (2.0f * inter + 1.0f) / (sp + st + 1.0f);
        out[0] = 0.5f * dice + 0.5f * (bce * invN)
               + 0.1f * (bnd * invN) + 0.2f * (foc * invN);
    }
}

extern "C" void kernel_launch(void* const* d_in, const int* in_sizes, int n_in,
                              void* d_out, int out_size, void* d_ws, size_t ws_size,
                              hipStream_t stream) {
    const float* pred = (const float*)d_in[0];
    const float* targ = (const float*)d_in[1];
    float* ws = (float*)d_ws;

    build_masks<<<64, 128, 0, stream>>>(pred, targ, ws);
    band_fused<<<BB * 64, 256, 0, stream>>>(pred, targ, ws, (float*)d_out);
}